// Round 9
// baseline (112.702 us; speedup 1.0000x reference)
//
#include <hip/hip_runtime.h>

#define PI_D 3.14159265358979323846
#define PI_F 3.14159265358979323846f

// ---- workspace layout (floats) ----
// U01 @ 0       : 1048576   U02 @ 1048576 : 1048576   U12 @ 2097152 : 262144
// V01 @ 2359296 : 524288    V02 @ 2883584 : 262144    V12 @ 3145728 : 131072
// P1p @ 3276800 : 128       P2p @ 3276928 : 64
// T01 @ 3276992 : 256       T02 @ 3277248 : 256       T12 @ 3277504 : 128

// Dirichlet tap, f64 (computed in k_front; consumers load precomputed tables).
// Analytically: Rl[0] = 1 and Rl[t] = 0 for t % s == 0 (t != 0, s = n1/n2).
__device__ inline float rtab_val(int n, int m2, int t) {
  if (t == 0) return 1.0f;
  double th = PI_D * (double)t / (double)n;
  double v = sin(th * (double)(m2 - 1)) / sin(th) + cos(th * (double)m2);
  return (float)(v / (double)m2);
}

// k_front: bid 0..191 P partials; 192..319 V01 (odd cols computed, even cols
// exact X1 copies); 320..447 V02; 448..511 V12. (proven R8 code, zero-block
// removed -- out zeroing moved to k_up, which precedes k_main's atomics.)
__global__ __launch_bounds__(256) void k_front(
    const float* __restrict__ X1, const float* __restrict__ X2,
    float* __restrict__ P1p, float* __restrict__ P2p, float* __restrict__ V01,
    float* __restrict__ V02, float* __restrict__ V12, float* __restrict__ T01,
    float* __restrict__ T02, float* __restrict__ T12) {
  __shared__ float fsm[2304];
  int bid = blockIdx.x;
  int t = threadIdx.x;
  if (bid < 192) {
    // ---- P partials ----
    const float* X; float* P; int lg, nsp, idx0;
    if (bid < 128) { X = X1; P = P1p; lg = 7; nsp = 8; idx0 = bid; }
    else           { X = X2; P = P2p; lg = 6; nsp = 4; idx0 = bid - 128; }
    int ch = idx0 / nsp, split = idx0 % nsp;
    int n = 1 << lg;
    int total = n * n;
    int chunk = total / nsp;
    int b0 = split * chunk;
    const float* x = X + (size_t)ch * total + b0;
    float s = 0.f;
    for (int i = t; i < chunk; i += 256) {
      int idx = b0 + i;
      float v = x[i];
      s += (((idx >> lg) ^ idx) & 1) ? -v : v;
    }
#pragma unroll
    for (int off = 32; off > 0; off >>= 1) s += __shfl_down(s, off, 64);
    __shared__ float red[4];
    if ((t & 63) == 0) red[t >> 6] = s;
    __syncthreads();
    if (t == 0) P[ch * nsp + split] = red[0] + red[1] + red[2] + red[3];
    return;
  }
  if (bid < 320) {
    // ---- V01: compute odd columns only; even columns copy X1 ----
    int idx = bid - 192;
    int ch = (idx & 7) + 8 * (idx >> 6);
    int nxg = ((idx >> 3) & 7) * 16;
    float* Rl = fsm;
    float* Xs = fsm + 256;
    for (int i = t; i < 256; i += 256) Rl[i] = rtab_val(256, 128, i);
    const float4* xch4 =
        (const float4*)(X1 + (size_t)ch * 16384 + (size_t)nxg * 128);
    for (int i = t; i < 512; i += 256) ((float4*)Xs)[i] = xch4[i];
    __syncthreads();
    if (idx == 0)
      for (int i = t; i < 256; i += 256) T01[i] = Rl[i];
    float* vch = V01 + (size_t)ch * 128 * 256;
    for (int i = t; i < 2048; i += 256) {
      int r = i >> 7, k = i & 127;
      vch[(size_t)(nxg + r) * 256 + 2 * k] = Xs[r * 128 + k];
    }
    int cid = t & 63, wq = t >> 6;
    int m0 = 2 * cid + 1, m1 = 2 * cid + 129;
    float acc[4][2];
#pragma unroll
    for (int r = 0; r < 4; ++r) { acc[r][0] = 0.f; acc[r][1] = 0.f; }
    for (int ny = 0; ny < 128; ++ny) {
      float r0 = Rl[(m0 - 2 * ny) & 255];
      float r1 = Rl[(m1 - 2 * ny) & 255];
#pragma unroll
      for (int r = 0; r < 4; ++r) {
        float xv = Xs[(4 * wq + r) * 128 + ny];
        acc[r][0] += xv * r0;
        acc[r][1] += xv * r1;
      }
    }
#pragma unroll
    for (int r = 0; r < 4; ++r) {
      vch[(size_t)(nxg + 4 * wq + r) * 256 + m0] = acc[r][0];
      vch[(size_t)(nxg + 4 * wq + r) * 256 + m1] = acc[r][1];
    }
    return;
  }
  // ---- V02 / V12 (full-column path) ----
  {
    int vbid = bid - 320;
    const float* X = X2; float* V;
    int n1, n2, s, ch, nxg, colh;
    if (vbid < 128) {
      V = V02; n1 = 256; n2 = 64; s = 4;
      ch = (vbid & 7) + 8 * (vbid >> 6);
      int sub = (vbid >> 3) & 7;
      nxg = ((sub >> 1) & 3) * 16; colh = sub & 1;
    } else {
      int w = vbid - 128;
      V = V12; n1 = 128; n2 = 64; s = 2;
      ch = (w & 7) + 8 * (w >> 5);
      nxg = ((w >> 3) & 3) * 16; colh = 0;
    }
    float* Rl = fsm;
    float* Xs = fsm + 256;
    for (int i = t; i < n1; i += 256) Rl[i] = rtab_val(n1, n2, i);
    const float4* xch4 =
        (const float4*)(X + (size_t)ch * n2 * n2 + (size_t)nxg * n2);
    int nx4 = (16 * n2) >> 2;
    for (int i = t; i < nx4; i += 256) ((float4*)Xs)[i] = xch4[i];
    __syncthreads();
    if (vbid == 0)
      for (int i = t; i < 256; i += 256) T02[i] = Rl[i];
    if (vbid == 128)
      for (int i = t; i < 128; i += 256) T12[i] = Rl[i];
    int myq = (t & 63) + colh * 128;
    int nxq = t >> 6;
    int mask = n1 - 1;
    float acc[4][2];
#pragma unroll
    for (int r = 0; r < 4; ++r)
#pragma unroll
      for (int c = 0; c < 2; ++c) acc[r][c] = 0.f;
    for (int ny = 0; ny < n2; ++ny) {
      float xv[4];
#pragma unroll
      for (int r = 0; r < 4; ++r) xv[r] = Xs[(4 * nxq + r) * n2 + ny];
#pragma unroll
      for (int c = 0; c < 2; ++c) {
        float rv = Rl[(myq + 64 * c - s * ny) & mask];
#pragma unroll
        for (int r = 0; r < 4; ++r) acc[r][c] += xv[r] * rv;
      }
    }
    float* vch = V + (size_t)ch * n2 * n1;
#pragma unroll
    for (int r = 0; r < 4; ++r)
      for (int c = 0; c < 2; ++c)
        vch[(size_t)(nxg + 4 * nxq + r) * n1 + myq + 64 * c] = acc[r][c];
  }
}

// k_up: materialize the full upsampled maps U = row-Dirichlet-interp of V,
// with the Nyquist correction folded in (it depends only on absolute row/col
// mod 2s and the per-channel Pv -- chunk-independent). Dirichlet-trivial rows
// (mx % s == 0) are exact V-row copies with zero correction.
//   bid 0..255   U01 (16 ch x 16 row-groups of 16; 8 odd rows computed)
//   bid 256..511 U02 (16 ch x 16 groups; 12 rows with mx%4!=0 computed)
//   bid 512..639 U12 (16 ch x 8 groups; 8 odd rows computed)
//   bid 640      zeroes out (runs before k_main's atomics)
__global__ __launch_bounds__(256) void k_up(
    const float* __restrict__ V01, const float* __restrict__ V02,
    const float* __restrict__ V12, const float* __restrict__ P1p,
    const float* __restrict__ P2p, const float* __restrict__ T01,
    const float* __restrict__ T02, const float* __restrict__ T12,
    float* __restrict__ U01, float* __restrict__ U02,
    float* __restrict__ U12, float* __restrict__ out) {
  __shared__ float sRl[256];
  __shared__ float Vt[2][2048];  // 8-row V tile, double-buffered (16 KB)
  int bid = blockIdx.x;
  int t = threadIdx.x;
  int lane = t & 63, wv = t >> 6;
  if (bid == 640) {
    for (int i = t; i < 5376; i += 256) out[i] = 0.f;
    return;
  }
  const float* V; const float* Pp; const float* T; float* U;
  int n1, n2, s, ch, grp, nsp; float inv;
  if (bid < 256) {
    V = V01; Pp = P1p; T = T01; U = U01; nsp = 8;
    n1 = 256; n2 = 128; s = 2; inv = 1.f / 16384.f;
    ch = bid >> 4; grp = bid & 15;
  } else if (bid < 512) {
    int w = bid - 256;
    V = V02; Pp = P2p; T = T02; U = U02; nsp = 4;
    n1 = 256; n2 = 64; s = 4; inv = 1.f / 4096.f;
    ch = w >> 4; grp = w & 15;
  } else {
    int w = bid - 512;
    V = V12; Pp = P2p; T = T12; U = U12; nsp = 4;
    n1 = 128; n2 = 64; s = 2; inv = 1.f / 4096.f;
    ch = w >> 3; grp = w & 7;
  }
  for (int i = t; i < n1; i += 256) sRl[i] = T[i];  // visible after tile-0 sync
  const float* vch = V + (size_t)ch * n2 * n1;
  float* uch = U + (size_t)ch * n1 * n1;
  float Pv = 0.f;
  for (int i = 0; i < nsp; ++i) Pv += Pp[ch * nsp + i];
  float a = PI_F / (float)s;
  int per = 2 * s;
  int r0g = grp * 16;
  const float4* vp4 = (const float4*)vch;

  if (n1 == 256) {
    // ---- trivial-row copies ----
    if (s == 2) {
      for (int i = t; i < 512; i += 256) {  // 8 rows x 64 f4
        int k = i >> 6, c4 = (i & 63) * 4;
        int mx = r0g + 2 * k;
        *(float4*)&uch[(size_t)mx * 256 + c4] =
            *(const float4*)(vch + (size_t)(mx >> 1) * 256 + c4);
      }
    } else {
      for (int i = t; i < 256; i += 256) {  // 4 rows x 64 f4
        int k = i >> 6, c4 = (i & 63) * 4;
        int mx = r0g + 4 * k;
        *(float4*)&uch[(size_t)mx * 256 + c4] =
            *(const float4*)(vch + (size_t)(mx >> 2) * 256 + c4);
      }
    }
    // ---- computed rows: per wave 2 (s=2: 4wv+{1,3}) or 3 (s=4: 4wv+{1,2,3})
    int nr = (s == 2) ? 2 : 3;
    int bj0 = r0g + 4 * wv + 1;
    int bj1 = r0g + 4 * wv + ((s == 2) ? 3 : 2);
    int bj2 = r0g + 4 * wv + 3;
    float4 acc0 = make_float4(0.f, 0.f, 0.f, 0.f);
    float4 acc1 = make_float4(0.f, 0.f, 0.f, 0.f);
    float4 acc2 = make_float4(0.f, 0.f, 0.f, 0.f);
    int ntl = n2 >> 3;  // 16 (U01) or 8 (U02) tiles
    for (int i = t; i < 512; i += 256) ((float4*)Vt[0])[i] = vp4[i];
    __syncthreads();
    for (int tl = 0; tl < ntl; ++tl) {
      float4 stg0, stg1;
      bool has = (tl + 1 < ntl);
      if (has) {
        stg0 = vp4[(size_t)(tl + 1) * 512 + t];
        stg1 = vp4[(size_t)(tl + 1) * 512 + 256 + t];
      }
      const float* Vc = Vt[tl & 1];
#pragma unroll
      for (int kk = 0; kk < 8; ++kk) {
        float4 vv = *(const float4*)&Vc[kk * 256 + 4 * lane];
        int ss = s * (8 * tl + kk);
        float r0v = sRl[(bj0 - ss) & 255];
        float r1v = sRl[(bj1 - ss) & 255];
        acc0.x += r0v * vv.x; acc0.y += r0v * vv.y;
        acc0.z += r0v * vv.z; acc0.w += r0v * vv.w;
        acc1.x += r1v * vv.x; acc1.y += r1v * vv.y;
        acc1.z += r1v * vv.z; acc1.w += r1v * vv.w;
        if (nr == 3) {
          float r2v = sRl[(bj2 - ss) & 255];
          acc2.x += r2v * vv.x; acc2.y += r2v * vv.y;
          acc2.z += r2v * vv.z; acc2.w += r2v * vv.w;
        }
      }
      if (has) {
        float4* d = (float4*)Vt[(tl & 1) ^ 1];
        d[t] = stg0;
        d[256 + t] = stg1;
      }
      __syncthreads();
    }
    float smy[4];
#pragma unroll
    for (int j = 0; j < 4; ++j)
      smy[j] = sinf(a * (float)((4 * lane + j) & (per - 1)));
    {
      float q = inv * sinf(a * (float)(bj0 & (per - 1))) * Pv;
      float4 o = acc0;
      o.x -= q * smy[0]; o.y -= q * smy[1]; o.z -= q * smy[2]; o.w -= q * smy[3];
      *(float4*)&uch[(size_t)bj0 * 256 + 4 * lane] = o;
    }
    {
      float q = inv * sinf(a * (float)(bj1 & (per - 1))) * Pv;
      float4 o = acc1;
      o.x -= q * smy[0]; o.y -= q * smy[1]; o.z -= q * smy[2]; o.w -= q * smy[3];
      *(float4*)&uch[(size_t)bj1 * 256 + 4 * lane] = o;
    }
    if (nr == 3) {
      float q = inv * sinf(a * (float)(bj2 & (per - 1))) * Pv;
      float4 o = acc2;
      o.x -= q * smy[0]; o.y -= q * smy[1]; o.z -= q * smy[2]; o.w -= q * smy[3];
      *(float4*)&uch[(size_t)bj2 * 256 + 4 * lane] = o;
    }
  } else {
    // ---- n1 = 128, s = 2 ----
    for (int i = t; i < 256; i += 256) {  // 8 rows x 32 f4
      int k = i >> 5, c4 = (i & 31) * 4;
      int mx = r0g + 2 * k;
      *(float4*)&uch[(size_t)mx * 128 + c4] =
          *(const float4*)(vch + (size_t)(mx >> 1) * 128 + c4);
    }
    int bj0 = r0g + 4 * wv + 1;
    int bj1 = r0g + 4 * wv + 3;
    float2 acc0 = make_float2(0.f, 0.f);
    float2 acc1 = make_float2(0.f, 0.f);
    for (int i = t; i < 256; i += 256) ((float4*)Vt[0])[i] = vp4[i];
    __syncthreads();
    for (int tl = 0; tl < 8; ++tl) {
      float4 stg0;
      bool has = (tl + 1 < 8);
      if (has) stg0 = vp4[(size_t)(tl + 1) * 256 + t];
      const float* Vc = Vt[tl & 1];
#pragma unroll
      for (int kk = 0; kk < 8; ++kk) {
        float2 vv = *(const float2*)&Vc[kk * 128 + 2 * lane];
        int ss = 2 * (8 * tl + kk);
        float r0v = sRl[(bj0 - ss) & 127];
        float r1v = sRl[(bj1 - ss) & 127];
        acc0.x += r0v * vv.x; acc0.y += r0v * vv.y;
        acc1.x += r1v * vv.x; acc1.y += r1v * vv.y;
      }
      if (has) ((float4*)Vt[(tl & 1) ^ 1])[t] = stg0;
      __syncthreads();
    }
    const float a2 = PI_F * 0.5f;
    float smy0 = sinf(a2 * (float)((2 * lane) & 3));
    float smy1 = sinf(a2 * (float)((2 * lane + 1) & 3));
    {
      float q = inv * sinf(a2 * (float)(bj0 & 3)) * Pv;
      float2 o = acc0; o.x -= q * smy0; o.y -= q * smy1;
      *(float2*)&uch[(size_t)bj0 * 128 + 2 * lane] = o;
    }
    {
      float q = inv * sinf(a2 * (float)(bj1 & 3)) * Pv;
      float2 o = acc1; o.x -= q * smy0; o.y -= q * smy1;
      *(float2*)&uch[(size_t)bj1 * 128 + 2 * lane] = o;
    }
  }
}

// k_main: 1088 UNIFORM blocks. Every block stages 19 rows of a global source
// (U channel for cross pairs; A2 channel for self pairs) into sh, then runs
// phase B + epilogue. LDS = 19.5 KB -> 8 blocks/CU = 32 waves/CU (full).
__global__ __launch_bounds__(256) void k_main(const float* __restrict__ X0,
                                              const float* __restrict__ X1,
                                              const float* __restrict__ X2,
                                              const float* __restrict__ U01,
                                              const float* __restrict__ U02,
                                              const float* __restrict__ U12,
                                              float* __restrict__ out) {
  __shared__ float sh[4864];  // 19-row window / epilogue (time-shared)
  int u = blockIdx.x;
  int t = threadIdx.x;
  int lane = t & 63, wv = t >> 6;
  const float* A1b; const float* S;
  int b, l2, base, lgn1, mxg;
  if (u < 640) {
    int ch, chunk;
    if (u < 256) {
      A1b = X0; lgn1 = 8; base = 64;
      ch = u >> 4; chunk = u & 15;
      S = U01 + (size_t)ch * 65536;
    } else if (u < 512) {
      int w = u - 256;
      A1b = X0; lgn1 = 8; base = 128;
      ch = w >> 4; chunk = w & 15;
      S = U02 + (size_t)ch * 65536;
    } else {
      int w = u - 512;
      A1b = X1; lgn1 = 7; base = 256;
      ch = w >> 3; chunk = w & 7;
      S = U12 + (size_t)ch * 16384;
    }
    b = ch >> 3; l2 = ch & 7; mxg = chunk * 16;
  } else {
    int w = u - 640;
    const float* Ab; int loc, lgc;
    if (w < 256)      { loc = w;       Ab = X0; lgn1 = 8; lgc = 4; base = 0;   }
    else if (w < 384) { loc = w - 256; Ab = X1; lgn1 = 7; lgc = 3; base = 192; }
    else              { loc = w - 384; Ab = X2; lgn1 = 6; lgc = 2; base = 320; }
    int n1sq = 1 << (2 * lgn1);
    int chunk = loc & ((1 << lgc) - 1);
    int bl2 = loc >> lgc;
    b = bl2 >> 3; l2 = bl2 & 7;
    A1b = Ab;
    S = Ab + (size_t)(b * 8 + l2) * n1sq;
    mxg = chunk * 16;
  }
  int n1 = 1 << lgn1, mask = n1 - 1;

  // ---- stage 19 rows [mxg-2, mxg+17) of S into sh (coalesced float4) ----
  int nst = (19 * n1) >> 2;
  int l2n1 = lgn1 - 2;
  for (int i = t; i < nst; i += 256) {
    int rl = i >> l2n1;
    int c4 = (i & ((n1 >> 2) - 1)) * 4;
    int src = (mxg - 2 + rl) & mask;
    *(float4*)&sh[rl * n1 + c4] = *(const float4*)(S + (size_t)src * n1 + c4);
  }
  __syncthreads();

  // ---- phase B: corr of A1 rows [mxg, mxg+16) against sh window ----
  float accC[8][7];
#pragma unroll
  for (int i = 0; i < 8; ++i)
#pragma unroll
    for (int p = 0; p < 7; ++p) accC[i][p] = 0.f;
  {
    int n1sq = n1 * n1;
    int lgtpr = lgn1 - 2;
    int tpr = 1 << lgtpr;
    int rif = 256 >> lgtpr;
    int rid = t >> lgtpr;
    int cid2 = t & (tpr - 1);
    int ty = cid2 * 4;
    int tym = (ty - 4) & mask;
    const float* A1 = A1b + (size_t)(b * 8) * n1sq;
    for (int rr = 0; rr < 16; rr += rif) {
      int ri = rr + rid;
      const float* r0 = &sh[(ri + 2) * n1];
      const float* r1 = &sh[(ri + 1) * n1];
      const float* r2 = &sh[ri * n1];
      const float* r3 = &sh[(ri + 3) * n1];
      float4 a0 = *(const float4*)(r0 + tym);
      float4 b0 = *(const float4*)(r0 + ty);
      float4 a1 = *(const float4*)(r1 + tym);
      float4 b1 = *(const float4*)(r1 + ty);
      float4 b2 = *(const float4*)(r2 + ty);
      float4 a3 = *(const float4*)(r3 + tym);
      float4 b3 = *(const float4*)(r3 + ty);
      const float* rA = A1 + (size_t)(mxg + ri) * n1 + ty;
#pragma unroll
      for (int l1 = 0; l1 < 8; ++l1) {
        float4 xv = *(const float4*)(rA + (size_t)l1 * n1sq);
        accC[l1][0] += xv.x * b0.x + xv.y * b0.y + xv.z * b0.z + xv.w * b0.w;
        accC[l1][1] += xv.x * a0.w + xv.y * b0.x + xv.z * b0.y + xv.w * b0.z;
        accC[l1][2] += xv.x * a0.z + xv.y * a0.w + xv.z * b0.x + xv.w * b0.y;
        accC[l1][3] += xv.x * b1.x + xv.y * b1.y + xv.z * b1.z + xv.w * b1.w;
        accC[l1][4] += xv.x * a1.w + xv.y * b1.x + xv.z * b1.y + xv.w * b1.z;
        accC[l1][5] += xv.x * b2.x + xv.y * b2.y + xv.z * b2.z + xv.w * b2.w;
        accC[l1][6] += xv.x * a3.w + xv.y * b3.x + xv.z * b3.y + xv.w * b3.z;
      }
    }
  }

  // ---- epilogue: 2-shfl fold + LDS transpose (stride 60) ----
  float* af = &accC[0][0];
#pragma unroll
  for (int j = 0; j < 56; ++j) {
    float v = af[j];
    v += __shfl_down(v, 32, 64);
    v += __shfl_down(v, 16, 64);
    af[j] = v;
  }
  __syncthreads();  // phase-B window reads done before epilogue overwrites sh
  if (lane < 16) {
    float* rowp = sh + (wv * 16 + lane) * 60;
#pragma unroll
    for (int j = 0; j < 14; ++j)
      *(float4*)&rowp[4 * j] =
          make_float4(af[4 * j], af[4 * j + 1], af[4 * j + 2], af[4 * j + 3]);
  }
  __syncthreads();
  if (t < 224) {
    int v = t >> 2, q = t & 3;
    float s2 = 0.f;
#pragma unroll
    for (int i = 0; i < 16; ++i) s2 += sh[(q * 16 + i) * 60 + v];
    s2 += __shfl_down(s2, 2, 64);
    s2 += __shfl_down(s2, 1, 64);
    if (q == 0) {
      int l1o = v / 7, p = v % 7;
      atomicAdd(&out[((size_t)b * 384 + base + l1o * 8 + l2) * 7 + p], s2);
    }
  }
}

extern "C" void kernel_launch(void* const* d_in, const int* in_sizes, int n_in,
                              void* d_out, int out_size, void* d_ws, size_t ws_size,
                              hipStream_t stream) {
  const float* X0 = (const float*)d_in[0];  // [2,8,256,256]
  const float* X1 = (const float*)d_in[1];  // [2,8,128,128]
  const float* X2 = (const float*)d_in[2];  // [2,8,64,64]
  float* out = (float*)d_out;               // [2,384,7]
  float* ws = (float*)d_ws;

  float* U01 = ws;
  float* U02 = ws + 1048576;
  float* U12 = ws + 2097152;
  float* V01 = ws + 2359296;
  float* V02 = ws + 2883584;
  float* V12 = ws + 3145728;
  float* P1p = ws + 3276800;
  float* P2p = ws + 3276928;
  float* T01 = ws + 3276992;
  float* T02 = ws + 3277248;
  float* T12 = ws + 3277504;

  k_front<<<512, 256, 0, stream>>>(X1, X2, P1p, P2p, V01, V02, V12, T01, T02,
                                   T12);
  k_up<<<641, 256, 0, stream>>>(V01, V02, V12, P1p, P2p, T01, T02, T12, U01,
                                U02, U12, out);
  k_main<<<1088, 256, 0, stream>>>(X0, X1, X2, U01, U02, U12, out);
}

// Round 10
// 109.338 us; speedup vs baseline: 1.0308x; 1.0308x over previous
//
#include <hip/hip_runtime.h>

#define PI_D 3.14159265358979323846
#define PI_F 3.14159265358979323846f

// Dirichlet tap, f64, computed per block (1 entry/thread; proven cheap in R0).
// Analytically: Rl[0] = 1 and Rl[t] = 0 for t % s == 0 (t != 0, s = n1/n2).
__device__ inline float rtab_val(int n, int m2, int t) {
  if (t == 0) return 1.0f;
  double th = PI_D * (double)t / (double)n;
  double v = sin(th * (double)(m2 - 1)) / sin(th) + cos(th * (double)m2);
  return (float)(v / (double)m2);
}

__global__ __launch_bounds__(256) void k_zero(float* __restrict__ out) {
  int i = blockIdx.x * 256 + threadIdx.x;
  if (i < 5376) out[i] = 0.f;
}

// k_all: 1088 self-contained blocks (no inter-kernel dependencies).
//   u < 640: cross-pair. Separable 2D Dirichlet upsample done block-locally:
//     (1) W = ROW-interp of X (19-row window, n2 cols) via the proven 8-row
//         double-buffered LDS staging; Pv (Nyquist sum) folds into the loads.
//     (2) COL-interp W -> full n1-col window in sh (W parked in the
//         Dirichlet-trivial column slots; interp fills the rest in place).
//     Sum interchange vs the old V-first pipeline -- mathematically identical.
//   u in [640,1088): self-pair, window = direct stage of A2 rows.
// Then one unified phase B + epilogue. LDS 28 KB -> 5 blocks/CU.
__global__ __launch_bounds__(256) void k_all(const float* __restrict__ X0,
                                             const float* __restrict__ X1,
                                             const float* __restrict__ X2,
                                             float* __restrict__ out) {
  __shared__ float sRl[256];
  __shared__ float sh[4864];   // 19-row window / epilogue (time-shared)
  __shared__ float Xt[2048];   // 2 x 8-row X tile (max 8x128 floats)
  __shared__ float red[4];
  int u = blockIdx.x;
  int t = threadIdx.x;
  int lane = t & 63, wv = t >> 6;
  int b, l2, base, lgn1, mxg;
  const float* A1b;

  if (u < 640) {
    // ================= cross-pair: build U window locally =================
    const float* Xsrc; int n1, n2, s, ch, chunk; float inv;
    if (u < 256) {
      A1b = X0; lgn1 = 8; base = 64; ch = u >> 4; chunk = u & 15;
      Xsrc = X1 + (size_t)ch * 16384; n1 = 256; n2 = 128; s = 2;
      inv = 1.f / 16384.f;
    } else if (u < 512) {
      int w = u - 256;
      A1b = X0; lgn1 = 8; base = 128; ch = w >> 4; chunk = w & 15;
      Xsrc = X2 + (size_t)ch * 4096; n1 = 256; n2 = 64; s = 4;
      inv = 1.f / 4096.f;
    } else {
      int w = u - 512;
      A1b = X1; lgn1 = 7; base = 256; ch = w >> 3; chunk = w & 7;
      Xsrc = X2 + (size_t)ch * 4096; n1 = 128; n2 = 64; s = 2;
      inv = 1.f / 4096.f;
    }
    int mask = n1 - 1;
    b = ch >> 3; l2 = ch & 7; mxg = chunk * 16;
    for (int i = t; i < n1; i += 256) sRl[i] = rtab_val(n1, n2, i);

    // ---- Dirichlet-trivial rows: copy X rows into the trivial column slots
    if (n1 == 256) {
      if (s == 2) {
        for (int i = t; i < 1280; i += 256) {  // 10 rows x 128
          int rl = 2 * (i >> 7), k = i & 127;
          int mx = (mxg - 2 + rl) & 255;
          sh[rl * 256 + 2 * k] = Xsrc[(size_t)(mx >> 1) * 128 + k];
        }
      } else {
        for (int i = t; i < 320; i += 256) {   // 5 rows x 64
          int rl = 2 + 4 * (i >> 6), k = i & 63;
          int mx = (mxg - 2 + rl) & 255;
          sh[rl * 256 + 4 * k] = Xsrc[(size_t)(mx >> 2) * 64 + k];
        }
      }
    } else {
      for (int i = t; i < 640; i += 256) {     // 10 rows x 64
        int rl = 2 * (i >> 6), k = i & 63;
        int mx = (mxg - 2 + rl) & 127;
        sh[rl * 128 + 2 * k] = Xsrc[(size_t)(mx >> 1) * 64 + k];
      }
    }

    const float4* xp4 = (const float4*)Xsrc;
    float pv = 0.f;

    if (n1 == 256 && s == 2) {
      // ======== U01: n2=128, 16 tiles of 8x128; 9 computed rows ========
      int nr; int rls[3];
      if (wv == 0)      { nr = 3; rls[0] = 1;  rls[1] = 3;  rls[2] = 5;  }
      else if (wv == 1) { nr = 2; rls[0] = 7;  rls[1] = 9;  rls[2] = 7;  }
      else if (wv == 2) { nr = 2; rls[0] = 11; rls[1] = 13; rls[2] = 11; }
      else              { nr = 2; rls[0] = 15; rls[1] = 17; rls[2] = 15; }
      int bj[3];
#pragma unroll
      for (int j = 0; j < 3; ++j) bj[j] = (mxg - 2 + rls[j]) & 255;
      float4 v0 = xp4[t];
      float rs = (float)(1 - 2 * ((t >> 5) & 1));
      pv += rs * (v0.x - v0.y + v0.z - v0.w);
      ((float4*)Xt)[t] = v0;
      __syncthreads();
      float2 acc[3];
#pragma unroll
      for (int j = 0; j < 3; ++j) acc[j] = make_float2(0.f, 0.f);
      for (int tl = 0; tl < 16; ++tl) {
        float4 stg;
        bool has = tl < 15;
        if (has) stg = xp4[(size_t)(tl + 1) * 256 + t];
        const float* Xc = &Xt[(tl & 1) * 1024];
#pragma unroll
        for (int kk = 0; kk < 8; ++kk) {
          float2 vv = *(const float2*)&Xc[kk * 128 + 2 * lane];
          int ss = 2 * (8 * tl + kk);
#pragma unroll
          for (int j = 0; j < 3; ++j)
            if (j < nr) {
              float rv = sRl[(bj[j] - ss) & 255];
              acc[j].x += rv * vv.x;
              acc[j].y += rv * vv.y;
            }
        }
        if (has) {
          pv += rs * (stg.x - stg.y + stg.z - stg.w);
          ((float4*)&Xt[((tl & 1) ^ 1) * 1024])[t] = stg;
        }
        __syncthreads();
      }
      // park W rows in even column slots
#pragma unroll
      for (int j = 0; j < 3; ++j)
        if (j < nr) {
          sh[rls[j] * 256 + 4 * lane] = acc[j].x;
          sh[rls[j] * 256 + 4 * lane + 2] = acc[j].y;
        }
#pragma unroll
      for (int off = 32; off > 0; off >>= 1) pv += __shfl_down(pv, off, 64);
      if (lane == 0) red[wv] = pv;
      __syncthreads();
      float Pv = red[0] + red[1] + red[2] + red[3];
      // ---- col-interp: odd columns (2 rows per iteration) ----
      int c = t & 127, half = t >> 7;
      int my = 2 * c + 1;
      float smy = ((my & 3) == 1) ? 1.f : -1.f;  // sin(pi/2 * (my mod 4))
      for (int it = 0; it < 10; ++it) {
        int rl = 2 * it + half;
        if (rl < 19) {
          const float* Wr = &sh[rl * 256];
          float sum = 0.f;
#pragma unroll 4
          for (int ny = 0; ny < 128; ++ny)
            sum += sRl[(my - 2 * ny) & 255] * Wr[2 * ny];
          int mxv = (mxg - 2 + rl) & 255;
          if (mxv & 1) {
            float qs = ((mxv & 3) == 1) ? 1.f : -1.f;
            sum -= inv * qs * smy * Pv;
          }
          sh[rl * 256 + my] = sum;
        }
      }
    } else if (n1 == 256) {
      // ======== U02: s=4, n2=64, 8 tiles of 8x64; 14 computed rows ========
      int nr; int rls[4];
      if (wv == 0)      { nr = 4; rls[0] = 0;  rls[1] = 1;  rls[2] = 3;  rls[3] = 4;  }
      else if (wv == 1) { nr = 4; rls[0] = 5;  rls[1] = 7;  rls[2] = 8;  rls[3] = 9;  }
      else if (wv == 2) { nr = 3; rls[0] = 11; rls[1] = 12; rls[2] = 13; rls[3] = 11; }
      else              { nr = 3; rls[0] = 15; rls[1] = 16; rls[2] = 17; rls[3] = 15; }
      int bj[4];
#pragma unroll
      for (int j = 0; j < 4; ++j) bj[j] = (mxg - 2 + rls[j]) & 255;
      float rs = (float)(1 - 2 * ((t >> 4) & 1));
      if (t < 128) {
        float4 v0 = xp4[t];
        pv += rs * (v0.x - v0.y + v0.z - v0.w);
        ((float4*)Xt)[t] = v0;
      }
      __syncthreads();
      float acc[4] = {0.f, 0.f, 0.f, 0.f};
      for (int tl = 0; tl < 8; ++tl) {
        float4 stg;
        bool has = (tl < 7) && (t < 128);
        if (has) stg = xp4[(size_t)(tl + 1) * 128 + t];
        const float* Xc = &Xt[(tl & 1) * 1024];
#pragma unroll
        for (int kk = 0; kk < 8; ++kk) {
          float vv = Xc[kk * 64 + lane];
          int ss = 4 * (8 * tl + kk);
#pragma unroll
          for (int j = 0; j < 4; ++j)
            if (j < nr) acc[j] += sRl[(bj[j] - ss) & 255] * vv;
        }
        if (has) {
          pv += rs * (stg.x - stg.y + stg.z - stg.w);
          ((float4*)&Xt[((tl & 1) ^ 1) * 1024])[t] = stg;
        }
        __syncthreads();
      }
#pragma unroll
      for (int j = 0; j < 4; ++j)
        if (j < nr) sh[rls[j] * 256 + 4 * lane] = acc[j];
#pragma unroll
      for (int off = 32; off > 0; off >>= 1) pv += __shfl_down(pv, off, 64);
      if (lane == 0) red[wv] = pv;
      __syncthreads();
      float Pv = red[0] + red[1] + red[2] + red[3];
      // ---- col-interp: cols with my%4 != 0 (192), one row per iteration ----
      const float aa = PI_F * 0.25f;
      if (t < 192) {
        int g = t / 3, r = t - 3 * g;
        int my = 4 * g + 1 + r;
        float smy = sinf(aa * (float)(my & 7));
        for (int rl = 0; rl < 19; ++rl) {
          const float* Wr = &sh[rl * 256];
          float sum = 0.f;
#pragma unroll 4
          for (int ny = 0; ny < 64; ++ny)
            sum += sRl[(my - 4 * ny) & 255] * Wr[4 * ny];
          int mxv = (mxg - 2 + rl) & 255;
          if (mxv & 3) sum -= inv * sinf(aa * (float)(mxv & 7)) * smy * Pv;
          sh[rl * 256 + my] = sum;
        }
      }
    } else {
      // ======== U12: n1=128, s=2, n2=64, 8 tiles; 9 computed rows ========
      int nr; int rls[3];
      if (wv == 0)      { nr = 3; rls[0] = 1;  rls[1] = 3;  rls[2] = 5;  }
      else if (wv == 1) { nr = 2; rls[0] = 7;  rls[1] = 9;  rls[2] = 7;  }
      else if (wv == 2) { nr = 2; rls[0] = 11; rls[1] = 13; rls[2] = 11; }
      else              { nr = 2; rls[0] = 15; rls[1] = 17; rls[2] = 15; }
      int bj[3];
#pragma unroll
      for (int j = 0; j < 3; ++j) bj[j] = (mxg - 2 + rls[j]) & 127;
      float rs = (float)(1 - 2 * ((t >> 4) & 1));
      if (t < 128) {
        float4 v0 = xp4[t];
        pv += rs * (v0.x - v0.y + v0.z - v0.w);
        ((float4*)Xt)[t] = v0;
      }
      __syncthreads();
      float acc[3] = {0.f, 0.f, 0.f};
      for (int tl = 0; tl < 8; ++tl) {
        float4 stg;
        bool has = (tl < 7) && (t < 128);
        if (has) stg = xp4[(size_t)(tl + 1) * 128 + t];
        const float* Xc = &Xt[(tl & 1) * 1024];
#pragma unroll
        for (int kk = 0; kk < 8; ++kk) {
          float vv = Xc[kk * 64 + lane];
          int ss = 2 * (8 * tl + kk);
#pragma unroll
          for (int j = 0; j < 3; ++j)
            if (j < nr) acc[j] += sRl[(bj[j] - ss) & 127] * vv;
        }
        if (has) {
          pv += rs * (stg.x - stg.y + stg.z - stg.w);
          ((float4*)&Xt[((tl & 1) ^ 1) * 1024])[t] = stg;
        }
        __syncthreads();
      }
#pragma unroll
      for (int j = 0; j < 3; ++j)
        if (j < nr) sh[rls[j] * 128 + 2 * lane] = acc[j];
#pragma unroll
      for (int off = 32; off > 0; off >>= 1) pv += __shfl_down(pv, off, 64);
      if (lane == 0) red[wv] = pv;
      __syncthreads();
      float Pv = red[0] + red[1] + red[2] + red[3];
      // ---- col-interp: odd columns (4 rows per iteration) ----
      int c = t & 63, sub = t >> 6;
      int my = 2 * c + 1;
      float smy = ((my & 3) == 1) ? 1.f : -1.f;
      for (int it = 0; it < 5; ++it) {
        int rl = 4 * it + sub;
        if (rl < 19) {
          const float* Wr = &sh[rl * 128];
          float sum = 0.f;
#pragma unroll 4
          for (int ny = 0; ny < 64; ++ny)
            sum += sRl[(my - 2 * ny) & 127] * Wr[2 * ny];
          int mxv = (mxg - 2 + rl) & 127;
          if (mxv & 1) {
            float qs = ((mxv & 3) == 1) ? 1.f : -1.f;
            sum -= inv * qs * smy * Pv;
          }
          sh[rl * 128 + my] = sum;
        }
      }
    }
  } else {
    // ================= self-pair: stage A2 window directly =================
    int w = u - 640;
    const float* Ab; int loc, lgc;
    if (w < 256)      { loc = w;       Ab = X0; lgn1 = 8; lgc = 4; base = 0;   }
    else if (w < 384) { loc = w - 256; Ab = X1; lgn1 = 7; lgc = 3; base = 192; }
    else              { loc = w - 384; Ab = X2; lgn1 = 6; lgc = 2; base = 320; }
    int n1 = 1 << lgn1;
    int mask = n1 - 1;
    int n1sq = n1 * n1;
    int chunk = loc & ((1 << lgc) - 1);
    int bl2 = loc >> lgc;
    b = bl2 >> 3; l2 = bl2 & 7;
    A1b = Ab;
    const float* S = Ab + (size_t)(b * 8 + l2) * n1sq;
    mxg = chunk * 16;
    int nst = (19 * n1) >> 2;
    int l2n1 = lgn1 - 2;
    for (int i = t; i < nst; i += 256) {
      int rl = i >> l2n1;
      int c4 = (i & ((n1 >> 2) - 1)) * 4;
      int src = (mxg - 2 + rl) & mask;
      *(float4*)&sh[rl * n1 + c4] = *(const float4*)(S + (size_t)src * n1 + c4);
    }
  }
  __syncthreads();

  // ---- unified phase B: corr of A1 rows [mxg, mxg+16) against sh window ----
  float accC[8][7];
#pragma unroll
  for (int i = 0; i < 8; ++i)
#pragma unroll
    for (int p = 0; p < 7; ++p) accC[i][p] = 0.f;
  {
    int n1 = 1 << lgn1;
    int mask = n1 - 1;
    int n1sq = n1 * n1;
    int lgtpr = lgn1 - 2;
    int tpr = 1 << lgtpr;
    int rif = 256 >> lgtpr;
    int rid = t >> lgtpr;
    int cid2 = t & (tpr - 1);
    int ty = cid2 * 4;
    int tym = (ty - 4) & mask;
    const float* A1 = A1b + (size_t)(b * 8) * n1sq;
    for (int rr = 0; rr < 16; rr += rif) {
      int ri = rr + rid;
      const float* r0 = &sh[(ri + 2) * n1];
      const float* r1 = &sh[(ri + 1) * n1];
      const float* r2 = &sh[ri * n1];
      const float* r3 = &sh[(ri + 3) * n1];
      float4 a0 = *(const float4*)(r0 + tym);
      float4 b0 = *(const float4*)(r0 + ty);
      float4 a1 = *(const float4*)(r1 + tym);
      float4 b1 = *(const float4*)(r1 + ty);
      float4 b2 = *(const float4*)(r2 + ty);
      float4 a3 = *(const float4*)(r3 + tym);
      float4 b3 = *(const float4*)(r3 + ty);
      const float* rA = A1 + (size_t)(mxg + ri) * n1 + ty;
#pragma unroll
      for (int l1 = 0; l1 < 8; ++l1) {
        float4 xv = *(const float4*)(rA + (size_t)l1 * n1sq);
        accC[l1][0] += xv.x * b0.x + xv.y * b0.y + xv.z * b0.z + xv.w * b0.w;
        accC[l1][1] += xv.x * a0.w + xv.y * b0.x + xv.z * b0.y + xv.w * b0.z;
        accC[l1][2] += xv.x * a0.z + xv.y * a0.w + xv.z * b0.x + xv.w * b0.y;
        accC[l1][3] += xv.x * b1.x + xv.y * b1.y + xv.z * b1.z + xv.w * b1.w;
        accC[l1][4] += xv.x * a1.w + xv.y * b1.x + xv.z * b1.y + xv.w * b1.z;
        accC[l1][5] += xv.x * b2.x + xv.y * b2.y + xv.z * b2.z + xv.w * b2.w;
        accC[l1][6] += xv.x * a3.w + xv.y * b3.x + xv.z * b3.y + xv.w * b3.z;
      }
    }
  }

  // ---- epilogue: 2-shfl fold + LDS transpose (stride 60) ----
  float* af = &accC[0][0];
#pragma unroll
  for (int j = 0; j < 56; ++j) {
    float v = af[j];
    v += __shfl_down(v, 32, 64);
    v += __shfl_down(v, 16, 64);
    af[j] = v;
  }
  __syncthreads();  // phase-B window reads done before epilogue overwrites sh
  if (lane < 16) {
    float* rowp = sh + (wv * 16 + lane) * 60;
#pragma unroll
    for (int j = 0; j < 14; ++j)
      *(float4*)&rowp[4 * j] =
          make_float4(af[4 * j], af[4 * j + 1], af[4 * j + 2], af[4 * j + 3]);
  }
  __syncthreads();
  if (t < 224) {
    int v = t >> 2, q = t & 3;
    float s2 = 0.f;
#pragma unroll
    for (int i = 0; i < 16; ++i) s2 += sh[(q * 16 + i) * 60 + v];
    s2 += __shfl_down(s2, 2, 64);
    s2 += __shfl_down(s2, 1, 64);
    if (q == 0) {
      int l1o = v / 7, p = v % 7;
      atomicAdd(&out[((size_t)b * 384 + base + l1o * 8 + l2) * 7 + p], s2);
    }
  }
}

extern "C" void kernel_launch(void* const* d_in, const int* in_sizes, int n_in,
                              void* d_out, int out_size, void* d_ws, size_t ws_size,
                              hipStream_t stream) {
  const float* X0 = (const float*)d_in[0];  // [2,8,256,256]
  const float* X1 = (const float*)d_in[1];  // [2,8,128,128]
  const float* X2 = (const float*)d_in[2];  // [2,8,64,64]
  float* out = (float*)d_out;               // [2,384,7]

  k_zero<<<21, 256, 0, stream>>>(out);
  k_all<<<1088, 256, 0, stream>>>(X0, X1, X2, out);
}

// Round 11
// 95.171 us; speedup vs baseline: 1.1842x; 1.1489x over previous
//
#include <hip/hip_runtime.h>

#define PI_D 3.14159265358979323846
#define PI_F 3.14159265358979323846f

// ---- workspace layout (floats) ----
// V01 @ 2359296 : 524288   V02 @ 2883584 : 262144   V12 @ 3145728 : 131072
// P1p @ 3276800 : 128      P2p @ 3276928 : 64
// T01 @ 3276992 : 256      T02 @ 3277248 : 256      T12 @ 3277504 : 128

// Dirichlet tap, f64 (computed in k_front; k_main loads precomputed tables).
// Analytically: Rl[0] = 1 and Rl[t] = 0 for t % s == 0 (t != 0, s = n1/n2).
__device__ inline float rtab_val(int n, int m2, int t) {
  if (t == 0) return 1.0f;
  double th = PI_D * (double)t / (double)n;
  double v = sin(th * (double)(m2 - 1)) / sin(th) + cos(th * (double)m2);
  return (float)(v / (double)m2);
}

// XCD alignment: V-builder blocks for channel ch and the fused k_main blocks
// that consume V[ch] are both mapped so blockIdx % 8 == (ch & 7) -- producer
// and consumer share an XCD L2 (dispatch round-robins XCDs by blockIdx % 8;
// perf heuristic only, correctness does not depend on it).

// k_front: bid 0..191 P partials; 192..319 V01 (odd cols computed, even cols
// exact X1 copies); 320..447 V02; 448..511 V12; 512 zeroes out. No atomics
// here, so the zero-block is race-free (all atomic writers live in k_main).
__global__ __launch_bounds__(256) void k_front(
    const float* __restrict__ X0, const float* __restrict__ X1,
    const float* __restrict__ X2, float* __restrict__ P1p,
    float* __restrict__ P2p, float* __restrict__ V01, float* __restrict__ V02,
    float* __restrict__ V12, float* __restrict__ T01, float* __restrict__ T02,
    float* __restrict__ T12, float* __restrict__ out) {
  __shared__ float fsm[2304];
  int bid = blockIdx.x;
  int t = threadIdx.x;
  if (bid == 512) {
    for (int i = t; i < 5376; i += 256) out[i] = 0.f;
    return;
  }
  if (bid < 192) {
    // ---- P partials ----
    const float* X; float* P; int lg, nsp, idx0;
    if (bid < 128) { X = X1; P = P1p; lg = 7; nsp = 8; idx0 = bid; }
    else           { X = X2; P = P2p; lg = 6; nsp = 4; idx0 = bid - 128; }
    int ch = idx0 / nsp, split = idx0 % nsp;
    int n = 1 << lg;
    int total = n * n;
    int chunk = total / nsp;
    int b0 = split * chunk;
    const float* x = X + (size_t)ch * total + b0;
    float s = 0.f;
    for (int i = t; i < chunk; i += 256) {
      int idx = b0 + i;
      float v = x[i];
      s += (((idx >> lg) ^ idx) & 1) ? -v : v;
    }
#pragma unroll
    for (int off = 32; off > 0; off >>= 1) s += __shfl_down(s, off, 64);
    __shared__ float red[4];
    if ((t & 63) == 0) red[t >> 6] = s;
    __syncthreads();
    if (t == 0) P[ch * nsp + split] = red[0] + red[1] + red[2] + red[3];
    return;
  }
  if (bid < 320) {
    // ---- V01: compute odd columns only; even columns copy X1 ----
    // XCD-aligned decode: idx = (ch&7) + 8*((ch>>3)*8 + j), j = col-group
    int idx = bid - 192;
    int ch = (idx & 7) + 8 * (idx >> 6);
    int nxg = ((idx >> 3) & 7) * 16;
    float* Rl = fsm;
    float* Xs = fsm + 256;
    for (int i = t; i < 256; i += 256) Rl[i] = rtab_val(256, 128, i);
    const float4* xch4 =
        (const float4*)(X1 + (size_t)ch * 16384 + (size_t)nxg * 128);
    for (int i = t; i < 512; i += 256) ((float4*)Xs)[i] = xch4[i];
    __syncthreads();
    if (idx == 0)
      for (int i = t; i < 256; i += 256) T01[i] = Rl[i];
    float* vch = V01 + (size_t)ch * 128 * 256;
    for (int i = t; i < 2048; i += 256) {
      int r = i >> 7, k = i & 127;
      vch[(size_t)(nxg + r) * 256 + 2 * k] = Xs[r * 128 + k];
    }
    int cid = t & 63, wq = t >> 6;
    int m0 = 2 * cid + 1, m1 = 2 * cid + 129;
    float acc[4][2];
#pragma unroll
    for (int r = 0; r < 4; ++r) { acc[r][0] = 0.f; acc[r][1] = 0.f; }
    for (int ny = 0; ny < 128; ++ny) {
      float r0 = Rl[(m0 - 2 * ny) & 255];
      float r1 = Rl[(m1 - 2 * ny) & 255];
#pragma unroll
      for (int r = 0; r < 4; ++r) {
        float xv = Xs[(4 * wq + r) * 128 + ny];
        acc[r][0] += xv * r0;
        acc[r][1] += xv * r1;
      }
    }
#pragma unroll
    for (int r = 0; r < 4; ++r) {
      vch[(size_t)(nxg + 4 * wq + r) * 256 + m0] = acc[r][0];
      vch[(size_t)(nxg + 4 * wq + r) * 256 + m1] = acc[r][1];
    }
    return;
  }
  // ---- V02 / V12 (full-column path), XCD-aligned decode ----
  {
    int vbid = bid - 320;
    const float* X = X2; float* V;
    int n1, n2, s, ch, nxg, colh;
    if (vbid < 128) {
      V = V02; n1 = 256; n2 = 64; s = 4;
      ch = (vbid & 7) + 8 * (vbid >> 6);
      int sub = (vbid >> 3) & 7;
      nxg = ((sub >> 1) & 3) * 16; colh = sub & 1;
    } else {
      int w = vbid - 128;
      V = V12; n1 = 128; n2 = 64; s = 2;
      ch = (w & 7) + 8 * (w >> 5);
      nxg = ((w >> 3) & 3) * 16; colh = 0;
    }
    float* Rl = fsm;
    float* Xs = fsm + 256;
    for (int i = t; i < n1; i += 256) Rl[i] = rtab_val(n1, n2, i);
    const float4* xch4 =
        (const float4*)(X + (size_t)ch * n2 * n2 + (size_t)nxg * n2);
    int nx4 = (16 * n2) >> 2;
    for (int i = t; i < nx4; i += 256) ((float4*)Xs)[i] = xch4[i];
    __syncthreads();
    if (vbid == 0)
      for (int i = t; i < 256; i += 256) T02[i] = Rl[i];
    if (vbid == 128)
      for (int i = t; i < 128; i += 256) T12[i] = Rl[i];
    int myq = (t & 63) + colh * 128;
    int nxq = t >> 6;
    int mask = n1 - 1;
    float acc[4][2];
#pragma unroll
    for (int r = 0; r < 4; ++r)
#pragma unroll
      for (int c = 0; c < 2; ++c) acc[r][c] = 0.f;
    for (int ny = 0; ny < n2; ++ny) {
      float xv[4];
#pragma unroll
      for (int r = 0; r < 4; ++r) xv[r] = Xs[(4 * nxq + r) * n2 + ny];
#pragma unroll
      for (int c = 0; c < 2; ++c) {
        float rv = Rl[(myq + 64 * c - s * ny) & mask];
#pragma unroll
        for (int r = 0; r < 4; ++r) acc[r][c] += xv[r] * rv;
      }
    }
    float* vch = V + (size_t)ch * n2 * n1;
#pragma unroll
    for (int r = 0; r < 4; ++r)
      for (int c = 0; c < 2; ++c)
        vch[(size_t)(nxg + 4 * nxq + r) * n1 + myq + 64 * c] = acc[r][c];
  }
}

// k_main: 1088 blocks, unified structure. Every block builds a 19-row window
// in sh then runs the same phase-B loop.
//   u < 640      fused: window = Dirichlet-interp of V. Phase A = 4-row tiles
//                staged through a 3-stage LDS pipeline (prefetch 2 tiles ahead
//                -> issue-to-use distance ~2 iterations > L3 latency).
//   u in [640,1088) self-corr: window = direct coalesced stage of A2 rows.
// LDS = 1K (sRl) + 19K (sh) + 12K (VsB) = 32 KB. Occupancy is VGPR-capped at
// 4 waves/SIMD (VGPR ~76-88), so further LDS shrinking does not pay (R5/R6/R10
// evidence).
__global__ __launch_bounds__(256) void k_main(const float* __restrict__ X0,
                                              const float* __restrict__ X1,
                                              const float* __restrict__ X2,
                                              const float* __restrict__ V01,
                                              const float* __restrict__ V02,
                                              const float* __restrict__ V12,
                                              const float* __restrict__ P1p,
                                              const float* __restrict__ P2p,
                                              const float* __restrict__ T01,
                                              const float* __restrict__ T02,
                                              const float* __restrict__ T12,
                                              float* __restrict__ out) {
  __shared__ float sRl[256];
  __shared__ float sh[4864];     // 19-row window / epilogue (time-shared)
  __shared__ float VsB[3072];    // 3 x 4-row V tile buffers (12 KB)
  int u = blockIdx.x;
  int t = threadIdx.x;
  int lane = t & 63;
  int wv = t >> 6;

  int b, l2, base, lgn1, mxg;
  const float* A1b;

  if (u < 640) {
    // ================= fused: interp window =================
    const float* V; const float* Pp; const float* T;
    int n1, n2, s, ch, chunk, nsp; float inv;
    if (u < 256) {
      // XCD-aligned: u = (ch&7) + 8*((ch>>3)*16 + chunk)
      V = V01; Pp = P1p; nsp = 8; A1b = X0; n1 = 256; n2 = 128; s = 2;
      inv = 1.f / 16384.f; lgn1 = 8; base = 64; T = T01;
      ch = (u & 7) + 8 * (u >> 7);
      chunk = (u >> 3) & 15;
    } else if (u < 512) {
      int w = u - 256;
      V = V02; Pp = P2p; nsp = 4; A1b = X0; n1 = 256; n2 = 64; s = 4;
      inv = 1.f / 4096.f; lgn1 = 8; base = 128; T = T02;
      ch = (w & 7) + 8 * (w >> 7);
      chunk = (w >> 3) & 15;
    } else {
      int w = u - 512;
      V = V12; Pp = P2p; nsp = 4; A1b = X1; n1 = 128; n2 = 64; s = 2;
      inv = 1.f / 4096.f; lgn1 = 7; base = 256; T = T12;
      ch = (w & 7) + 8 * (w >> 6);
      chunk = (w >> 3) & 7;
    }
    int mask = n1 - 1;
    for (int i = t; i < n1; i += 256) sRl[i] = T[i];  // visible after prologue sync
    mxg = chunk * 16;
    b = ch >> 3; l2 = ch & 7;
    const float* vch = V + (size_t)ch * n2 * n1;
    float Pv = 0.f;
    for (int i = 0; i < nsp; ++i) Pv += Pp[ch * nsp + i];
    float a = PI_F / (float)s;
    int per = 2 * s;

    // ---- Dirichlet-trivial rows: exact V-row copies (block-wide, up-front) ----
    if (n1 == 256) {
      if (s == 2) {
        for (int i = t; i < 640; i += 256) {
          int rl = 2 * (i >> 6), c4 = (i & 63) * 4;
          int mx = (mxg - 2 + rl) & 255;
          *(float4*)&sh[rl * 256 + c4] =
              *(const float4*)(vch + (size_t)(mx >> 1) * 256 + c4);
        }
      } else {
        for (int i = t; i < 320; i += 256) {
          int rl = 2 + 4 * (i >> 6), c4 = (i & 63) * 4;
          int mx = (mxg - 2 + rl) & 255;
          *(float4*)&sh[rl * 256 + c4] =
              *(const float4*)(vch + (size_t)(mx >> 2) * 256 + c4);
        }
      }
    } else {
      for (int i = t; i < 320; i += 256) {
        int rl = 2 * (i >> 5), c4 = (i & 31) * 4;
        int mx = (mxg - 2 + rl) & 127;
        *(float4*)&sh[rl * 128 + c4] =
            *(const float4*)(vch + (size_t)(mx >> 1) * 128 + c4);
      }
    }

    // ---- per-wave interp-row assignment ----
    int nr, rls[4];
    if (s == 2) {  // 9 rows: {1,3,5},{7,9},{11,13},{15,17}
      if (wv == 0)      { nr = 3; rls[0] = 1;  rls[1] = 3;  rls[2] = 5;  rls[3] = 1; }
      else if (wv == 1) { nr = 2; rls[0] = 7;  rls[1] = 9;  rls[2] = 7;  rls[3] = 7; }
      else if (wv == 2) { nr = 2; rls[0] = 11; rls[1] = 13; rls[2] = 11; rls[3] = 11; }
      else              { nr = 2; rls[0] = 15; rls[1] = 17; rls[2] = 15; rls[3] = 15; }
    } else {       // 14 rows: {0,1,3,4},{5,7,8,9},{11,12,13},{15,16,17}
      if (wv == 0)      { nr = 4; rls[0] = 0;  rls[1] = 1;  rls[2] = 3;  rls[3] = 4; }
      else if (wv == 1) { nr = 4; rls[0] = 5;  rls[1] = 7;  rls[2] = 8;  rls[3] = 9; }
      else if (wv == 2) { nr = 3; rls[0] = 11; rls[1] = 12; rls[2] = 13; rls[3] = 11; }
      else              { nr = 3; rls[0] = 15; rls[1] = 16; rls[2] = 17; rls[3] = 15; }
    }
    int bj[4];
#pragma unroll
    for (int j = 0; j < 4; ++j) bj[j] = (mxg - 2 + rls[j]) & mask;

    // ---- staged tap loop: 4-row tiles, 3-stage pipeline (prefetch 2 ahead) ----
    const float4* vp4 = (const float4*)vch;
    if (n1 == 256) {
      int ntl = n2 >> 2;  // 32 (s=2) or 16 (s=4) tiles; even, >= 16
      float* bc = VsB;
      float* bn = VsB + 1024;
      float* bo = VsB + 2048;
      ((float4*)bc)[t] = vp4[t];
      float4 rA = vp4[256 + t];
      float4 rB = vp4[512 + t];
      __syncthreads();
      float4 acc[4];
#pragma unroll
      for (int j = 0; j < 4; ++j) acc[j] = make_float4(0.f, 0.f, 0.f, 0.f);
      for (int tl = 0; tl < ntl; tl += 2) {
        // even sub-iter: compute tile tl; commit rA (tile tl+1); issue tl+3
        {
          const float* Vc = bc;
#pragma unroll
          for (int kk = 0; kk < 4; ++kk) {
            float4 vv = *(const float4*)&Vc[kk * 256 + 4 * lane];
            int ss = s * (4 * tl + kk);
#pragma unroll
            for (int j = 0; j < 4; ++j)
              if (j < nr) {
                float rv = sRl[(bj[j] - ss) & 255];
                acc[j].x += rv * vv.x;
                acc[j].y += rv * vv.y;
                acc[j].z += rv * vv.z;
                acc[j].w += rv * vv.w;
              }
          }
          if (tl + 1 < ntl) ((float4*)bn)[t] = rA;
          if (tl + 3 < ntl) rA = vp4[(size_t)(tl + 3) * 256 + t];
          __syncthreads();
          float* tmp = bc; bc = bn; bn = bo; bo = tmp;
        }
        // odd sub-iter: compute tile tl+1; commit rB (tile tl+2); issue tl+4
        {
          const float* Vc = bc;
#pragma unroll
          for (int kk = 0; kk < 4; ++kk) {
            float4 vv = *(const float4*)&Vc[kk * 256 + 4 * lane];
            int ss = s * (4 * (tl + 1) + kk);
#pragma unroll
            for (int j = 0; j < 4; ++j)
              if (j < nr) {
                float rv = sRl[(bj[j] - ss) & 255];
                acc[j].x += rv * vv.x;
                acc[j].y += rv * vv.y;
                acc[j].z += rv * vv.z;
                acc[j].w += rv * vv.w;
              }
          }
          if (tl + 2 < ntl) ((float4*)bn)[t] = rB;
          if (tl + 4 < ntl) rB = vp4[(size_t)(tl + 4) * 256 + t];
          __syncthreads();
          float* tmp = bc; bc = bn; bn = bo; bo = tmp;
        }
      }
      float smy[4];
#pragma unroll
      for (int j = 0; j < 4; ++j)
        smy[j] = sinf(a * (float)((4 * lane + j) & (per - 1)));
#pragma unroll
      for (int j = 0; j < 4; ++j)
        if (j < nr) {
          float q = inv * sinf(a * (float)(bj[j] & (per - 1))) * Pv;
          float4 o = acc[j];
          o.x -= q * smy[0];
          o.y -= q * smy[1];
          o.z -= q * smy[2];
          o.w -= q * smy[3];
          *(float4*)&sh[rls[j] * 256 + 4 * lane] = o;
        }
    } else {  // n1 == 128, s = 2, n2 = 64 -> 16 tiles of 128 float4
      float* bc = VsB;
      float* bn = VsB + 512;
      float* bo = VsB + 1024;
      float4 rA, rB;
      if (t < 128) {
        ((float4*)bc)[t] = vp4[t];
        rA = vp4[128 + t];
        rB = vp4[256 + t];
      }
      __syncthreads();
      float2 acc[4];
#pragma unroll
      for (int j = 0; j < 4; ++j) acc[j] = make_float2(0.f, 0.f);
      for (int tl = 0; tl < 16; tl += 2) {
        {
          const float* Vc = bc;
#pragma unroll
          for (int kk = 0; kk < 4; ++kk) {
            float2 vv = *(const float2*)&Vc[kk * 128 + 2 * lane];
            int ss = 2 * (4 * tl + kk);
#pragma unroll
            for (int j = 0; j < 4; ++j)
              if (j < nr) {
                float rv = sRl[(bj[j] - ss) & 127];
                acc[j].x += rv * vv.x;
                acc[j].y += rv * vv.y;
              }
          }
          if (t < 128) {
            if (tl + 1 < 16) ((float4*)bn)[t] = rA;
            if (tl + 3 < 16) rA = vp4[(size_t)(tl + 3) * 128 + t];
          }
          __syncthreads();
          float* tmp = bc; bc = bn; bn = bo; bo = tmp;
        }
        {
          const float* Vc = bc;
#pragma unroll
          for (int kk = 0; kk < 4; ++kk) {
            float2 vv = *(const float2*)&Vc[kk * 128 + 2 * lane];
            int ss = 2 * (4 * (tl + 1) + kk);
#pragma unroll
            for (int j = 0; j < 4; ++j)
              if (j < nr) {
                float rv = sRl[(bj[j] - ss) & 127];
                acc[j].x += rv * vv.x;
                acc[j].y += rv * vv.y;
              }
          }
          if (t < 128) {
            if (tl + 2 < 16) ((float4*)bn)[t] = rB;
            if (tl + 4 < 16) rB = vp4[(size_t)(tl + 4) * 128 + t];
          }
          __syncthreads();
          float* tmp = bc; bc = bn; bn = bo; bo = tmp;
        }
      }
      const float a2 = PI_F * 0.5f;
      float smy0 = sinf(a2 * (float)((2 * lane) & 3));
      float smy1 = sinf(a2 * (float)((2 * lane + 1) & 3));
#pragma unroll
      for (int j = 0; j < 4; ++j)
        if (j < nr) {
          float q = inv * sinf(a2 * (float)(bj[j] & 3)) * Pv;
          float2 o = acc[j];
          o.x -= q * smy0;
          o.y -= q * smy1;
          *(float2*)&sh[rls[j] * 128 + 2 * lane] = o;
        }
    }
  } else {
    // ================= self-corr: stage A2 window directly =================
    int w = u - 640;
    const float* Ab; int loc, lgc;
    if (w < 256)      { loc = w;       Ab = X0; lgn1 = 8; lgc = 4; base = 0;   }
    else if (w < 384) { loc = w - 256; Ab = X1; lgn1 = 7; lgc = 3; base = 192; }
    else              { loc = w - 384; Ab = X2; lgn1 = 6; lgc = 2; base = 320; }
    int n1 = 1 << lgn1;
    int mask = n1 - 1;
    int n1sq = n1 * n1;
    int chunk = loc & ((1 << lgc) - 1);
    int bl2 = loc >> lgc;
    b = bl2 >> 3; l2 = bl2 & 7;
    A1b = Ab;
    const float* A2 = Ab + (size_t)(b * 8 + l2) * n1sq;
    mxg = chunk * 16;
    // stage 19 rows [mxg-2, mxg+17) of A2 into sh (coalesced float4)
    int nst = (19 * n1) >> 2;
    int l2n1 = lgn1 - 2;  // log2(n1/4)
    for (int i = t; i < nst; i += 256) {
      int rl = i >> l2n1;
      int c4 = (i & ((n1 >> 2) - 1)) * 4;
      int src = (mxg - 2 + rl) & mask;
      *(float4*)&sh[rl * n1 + c4] = *(const float4*)(A2 + (size_t)src * n1 + c4);
    }
  }
  __syncthreads();

  // ---- unified phase B: corr of A1 rows [mxg, mxg+16) against sh window ----
  float accC[8][7];
#pragma unroll
  for (int i = 0; i < 8; ++i)
#pragma unroll
    for (int p = 0; p < 7; ++p) accC[i][p] = 0.f;
  {
    int n1 = 1 << lgn1;
    int mask = n1 - 1;
    int n1sq = n1 * n1;
    int lgtpr = lgn1 - 2;
    int tpr = 1 << lgtpr;
    int rif = 256 >> lgtpr;
    int rid = t >> lgtpr;
    int cid2 = t & (tpr - 1);
    int ty = cid2 * 4;
    int tym = (ty - 4) & mask;
    const float* A1 = A1b + (size_t)(b * 8) * n1sq;
    for (int rr = 0; rr < 16; rr += rif) {
      int ri = rr + rid;
      const float* r0 = &sh[(ri + 2) * n1];
      const float* r1 = &sh[(ri + 1) * n1];
      const float* r2 = &sh[ri * n1];
      const float* r3 = &sh[(ri + 3) * n1];
      float4 a0 = *(const float4*)(r0 + tym);
      float4 b0 = *(const float4*)(r0 + ty);
      float4 a1 = *(const float4*)(r1 + tym);
      float4 b1 = *(const float4*)(r1 + ty);
      float4 b2 = *(const float4*)(r2 + ty);
      float4 a3 = *(const float4*)(r3 + tym);
      float4 b3 = *(const float4*)(r3 + ty);
      const float* rA = A1 + (size_t)(mxg + ri) * n1 + ty;
#pragma unroll
      for (int l1 = 0; l1 < 8; ++l1) {
        float4 xv = *(const float4*)(rA + (size_t)l1 * n1sq);
        accC[l1][0] += xv.x * b0.x + xv.y * b0.y + xv.z * b0.z + xv.w * b0.w;
        accC[l1][1] += xv.x * a0.w + xv.y * b0.x + xv.z * b0.y + xv.w * b0.z;
        accC[l1][2] += xv.x * a0.z + xv.y * a0.w + xv.z * b0.x + xv.w * b0.y;
        accC[l1][3] += xv.x * b1.x + xv.y * b1.y + xv.z * b1.z + xv.w * b1.w;
        accC[l1][4] += xv.x * a1.w + xv.y * b1.x + xv.z * b1.y + xv.w * b1.z;
        accC[l1][5] += xv.x * b2.x + xv.y * b2.y + xv.z * b2.z + xv.w * b2.w;
        accC[l1][6] += xv.x * a3.w + xv.y * b3.x + xv.z * b3.y + xv.w * b3.z;
      }
    }
  }

  // ---- epilogue: 2-shfl fold + LDS transpose (stride 60) ----
  float* af = &accC[0][0];
#pragma unroll
  for (int j = 0; j < 56; ++j) {
    float v = af[j];
    v += __shfl_down(v, 32, 64);
    v += __shfl_down(v, 16, 64);
    af[j] = v;
  }
  __syncthreads();  // phase-B window reads done before epilogue overwrites sh
  if (lane < 16) {
    float* rowp = sh + (wv * 16 + lane) * 60;
#pragma unroll
    for (int j = 0; j < 14; ++j)
      *(float4*)&rowp[4 * j] =
          make_float4(af[4 * j], af[4 * j + 1], af[4 * j + 2], af[4 * j + 3]);
  }
  __syncthreads();
  if (t < 224) {
    int v = t >> 2, q = t & 3;
    float s2 = 0.f;
#pragma unroll
    for (int i = 0; i < 16; ++i) s2 += sh[(q * 16 + i) * 60 + v];
    s2 += __shfl_down(s2, 2, 64);
    s2 += __shfl_down(s2, 1, 64);
    if (q == 0) {
      int l1o = v / 7, p = v % 7;
      atomicAdd(&out[((size_t)b * 384 + base + l1o * 8 + l2) * 7 + p], s2);
    }
  }
}

extern "C" void kernel_launch(void* const* d_in, const int* in_sizes, int n_in,
                              void* d_out, int out_size, void* d_ws, size_t ws_size,
                              hipStream_t stream) {
  const float* X0 = (const float*)d_in[0];  // [2,8,256,256]
  const float* X1 = (const float*)d_in[1];  // [2,8,128,128]
  const float* X2 = (const float*)d_in[2];  // [2,8,64,64]
  float* out = (float*)d_out;               // [2,384,7]
  float* ws = (float*)d_ws;

  float* V01 = ws + 2359296;
  float* V02 = ws + 2883584;
  float* V12 = ws + 3145728;
  float* P1p = ws + 3276800;
  float* P2p = ws + 3276928;
  float* T01 = ws + 3276992;
  float* T02 = ws + 3277248;
  float* T12 = ws + 3277504;

  k_front<<<513, 256, 0, stream>>>(X0, X1, X2, P1p, P2p, V01, V02, V12, T01,
                                   T02, T12, out);
  k_main<<<1088, 256, 0, stream>>>(X0, X1, X2, V01, V02, V12, P1p, P2p, T01,
                                   T02, T12, out);
}